// Round 12
// baseline (487.589 us; speedup 1.0000x reference)
//
#include <hip/hip_runtime.h>

// ---------------------------------------------------------------------------
// DeformableTransformerEncoderLayer on MI355X (gfx950)
// B=4, LQ=13294, DM=256, DFFN=1024, NL=4, NH=8, NP=4, HD=32
// M = 53176 rows, padded tiles to Mp = 53248 = 416*128.
// Round 12:
//  - value stored FP32 head-major (ws permitting): kills the 8x bf2f shift
//    per bilinear corner in sample_k (~40% of its VALU stream). f32x4
//    vector accumulate (v_pk_fma_f32-friendly).
//  - Workspace-gated configs: A fp32 value + bf16 src resid; B fp32 value;
//    C = round-11 bf16 fallback.
// Pipeline (9 dispatches):
//   prep_all (+q_bf,+src_bf); G1 value; G2 offaw; sample; G4LN x_bf;
//   2x { G5 h; G6LN d_out }
// ---------------------------------------------------------------------------

#define LQn   13294
#define MREAL 53176
#define MP    53248
#define MT    416
#define MHALF 26588
#define MTH   208

typedef __attribute__((ext_vector_type(8))) short short8;
typedef __attribute__((ext_vector_type(4))) short short4v;
typedef __attribute__((ext_vector_type(4))) float f32x4;

__device__ __forceinline__ short f2bf(float f) {
    unsigned u = __float_as_uint(f);
    unsigned r = (u + 0x7FFFu + ((u >> 16) & 1u)) >> 16;  // RNE
    return (short)r;
}
__device__ __forceinline__ float bf2f(short b) {
    return __uint_as_float(((unsigned)(unsigned short)b) << 16);
}

#define GLOAD16(gp, lp)                                                        \
    __builtin_amdgcn_global_load_lds(                                          \
        (const __attribute__((address_space(1))) void*)(gp),                   \
        (__attribute__((address_space(3))) void*)(lp), 16, 0, 0)

// ---------------------------------------------------------------------------
// Weight prep + bias concat + q_bf / src_bf, all in ONE dispatch.
// ---------------------------------------------------------------------------
__global__ __launch_bounds__(256) void prep_all(
    const float* __restrict__ Wv, const float* __restrict__ Ws,
    const float* __restrict__ Wa, const float* __restrict__ Wo,
    const float* __restrict__ W1, const float* __restrict__ W2,
    const float* __restrict__ bs, const float* __restrict__ ba,
    const float* __restrict__ src, const float* __restrict__ pos,
    short* __restrict__ WvT, short* __restrict__ WsaT,
    short* __restrict__ WoT, short* __restrict__ W1T,
    short* __restrict__ W2T, float* __restrict__ bsa,
    short* __restrict__ q_bf, short* __restrict__ src_bf) {
    const int bid = blockIdx.x, tid = threadIdx.x;
    if (bid >= 2945) {
        const int i = (bid - 2945) * 256 + tid;
        if (i < MREAL * 32) {
            const float4 a0 = ((const float4*)src)[i * 2];
            const float4 a1 = ((const float4*)src)[i * 2 + 1];
            const float4 b0 = ((const float4*)pos)[i * 2];
            const float4 b1 = ((const float4*)pos)[i * 2 + 1];
            short8 o, o2;
            o[0] = f2bf(a0.x + b0.x); o[1] = f2bf(a0.y + b0.y);
            o[2] = f2bf(a0.z + b0.z); o[3] = f2bf(a0.w + b0.w);
            o[4] = f2bf(a1.x + b1.x); o[5] = f2bf(a1.y + b1.y);
            o[6] = f2bf(a1.z + b1.z); o[7] = f2bf(a1.w + b1.w);
            o2[0] = f2bf(a0.x); o2[1] = f2bf(a0.y);
            o2[2] = f2bf(a0.z); o2[3] = f2bf(a0.w);
            o2[4] = f2bf(a1.x); o2[5] = f2bf(a1.y);
            o2[6] = f2bf(a1.z); o2[7] = f2bf(a1.w);
            ((short8*)q_bf)[i] = o;
            ((short8*)src_bf)[i] = o2;
        }
        return;
    }
    const float* W; short* WT; int K, N, base;
    if (bid < 256)       { W = Wv; WT = WvT;              K = 256;  N = 256;  base = 0; }
    else if (bid < 512)  { W = Ws; WT = WsaT;             K = 256;  N = 256;  base = 256; }
    else if (bid < 640)  { W = Wa; WT = WsaT + 256 * 256; K = 256;  N = 128;  base = 512; }
    else if (bid < 896)  { W = Wo; WT = WoT;              K = 256;  N = 256;  base = 640; }
    else if (bid < 1920) { W = W1; WT = W1T;              K = 256;  N = 1024; base = 896; }
    else if (bid < 2944) { W = W2; WT = W2T;              K = 1024; N = 256;  base = 1920; }
    else {
        if (tid < 256) bsa[tid] = bs[tid];
        else if (tid < 384) bsa[tid] = ba[tid - 256];
        return;
    }
    const int i = (bid - base) * 256 + tid;
    const int n = i / K, k = i - n * K;
    WT[i] = f2bf(W[(size_t)k * N + n]);
}

// ---------------------------------------------------------------------------
// bf16 MFMA GEMM. 128x128 tile, BK=32, 4 waves, 16x16x32 MFMA.
// Dbuf global_load_lds staging; NT-swizzled 1-D grid (A-tile L2 locality).
// EPI: 1 = bf16+bias (bounce); 2 = relu->bf16+bias (bounce);
//      5 = bf16+bias head-major scatter (bounce);
//      6 = fp32+bias head-major scatter (direct stores)
// ---------------------------------------------------------------------------
template <int EPI, int NT>
__global__ __launch_bounds__(256) void gemm_bt(const short* __restrict__ Ab,
                                               const short* __restrict__ BT,
                                               const float* __restrict__ bias,
                                               void* C,
                                               int M, int K, int N,
                                               int ldb, int ldc) {
    const int d = blockIdx.x;
    const int c = d & 7, j = d >> 3;
    const int jg = j / NT;
    const int m0 = (c + 8 * jg) * 128;
    const int n0 = (j - jg * NT) * 128;
    const int t = threadIdx.x;
    const int wid = t >> 6, lane = t & 63;
    const int wr = wid >> 1, wc = wid & 1;
    const int quad = lane >> 4, l16 = lane & 15;

    __shared__ short lA[2][128 * 32];
    __shared__ short lB[2][128 * 32];

    f32x4 acc[4][4];
#pragma unroll
    for (int i = 0; i < 4; ++i)
#pragma unroll
        for (int jj = 0; jj < 4; ++jj) acc[i][jj] = (f32x4){0.f, 0.f, 0.f, 0.f};

    const int grow = wid * 32 + (lane >> 2);
    const int gcol = (lane & 3) * 8;
    auto stage = [&](int buf, int k0) {
        GLOAD16(Ab + (size_t)(m0 + grow) * K + k0 + gcol,
                &lA[buf][(wid * 32) * 32]);
        GLOAD16(Ab + (size_t)(m0 + grow + 16) * K + k0 + gcol,
                &lA[buf][(wid * 32 + 16) * 32]);
        GLOAD16(BT + (size_t)(n0 + grow) * ldb + k0 + gcol,
                &lB[buf][(wid * 32) * 32]);
        GLOAD16(BT + (size_t)(n0 + grow + 16) * ldb + k0 + gcol,
                &lB[buf][(wid * 32 + 16) * 32]);
    };
    stage(0, 0);
    __syncthreads();
    int cur = 0;
    for (int k0 = 0; k0 < K; k0 += 32) {
        if (k0 + 32 < K) stage(cur ^ 1, k0 + 32);
        short8 af[4], bfr[4];
#pragma unroll
        for (int mi = 0; mi < 4; ++mi)
            af[mi] = *(const short8*)&lA[cur][(wr * 64 + mi * 16 + l16) * 32 + quad * 8];
#pragma unroll
        for (int ni = 0; ni < 4; ++ni)
            bfr[ni] = *(const short8*)&lB[cur][(wc * 64 + ni * 16 + l16) * 32 + quad * 8];
#pragma unroll
        for (int mi = 0; mi < 4; ++mi)
#pragma unroll
            for (int ni = 0; ni < 4; ++ni)
                acc[mi][ni] = __builtin_amdgcn_mfma_f32_16x16x32_bf16(
                    af[mi], bfr[ni], acc[mi][ni], 0, 0, 0);
        __syncthreads();
        cur ^= 1;
    }

    if (EPI == 6) {
        // direct fp32 head-major scatter
#pragma unroll
        for (int ni = 0; ni < 4; ++ni) {
            const int gc = n0 + wc * 64 + ni * 16 + l16;
            const float bia = bias[gc];
            const int hh = gc >> 5, dd = gc & 31;
#pragma unroll
            for (int mi = 0; mi < 4; ++mi)
#pragma unroll
                for (int r = 0; r < 4; ++r) {
                    const int gr = m0 + wr * 64 + mi * 16 + quad * 4 + r;
                    if (gr < M) {
                        const int b = gr / LQn, s = gr - b * LQn;
                        ((float*)C)[(((size_t)b * 8 + hh) * LQn + s) * 32 + dd] =
                            acc[mi][ni][r] + bia;
                    }
                }
        }
        return;
    }

    // ---- LDS-bounce vectorized epilogue: 2 passes of 64 cols ----
    short* lflat = (short*)lA;  // 8192 shorts = 128 x 64
#pragma unroll
    for (int p = 0; p < 2; ++p) {
        if (wc == p) {
#pragma unroll
            for (int ni = 0; ni < 4; ++ni) {
                const int lc = ni * 16 + l16;
                const float bia = bias[n0 + p * 64 + lc];
#pragma unroll
                for (int mi = 0; mi < 4; ++mi)
#pragma unroll
                    for (int r = 0; r < 4; ++r) {
                        const int lr = wr * 64 + mi * 16 + quad * 4 + r;
                        float v = acc[mi][ni][r] + bia;
                        if (EPI == 2) v = fmaxf(v, 0.f);
                        lflat[lr * 64 + (lc ^ ((lr & 7) << 3))] = f2bf(v);
                    }
            }
        }
        __syncthreads();
#pragma unroll
        for (int i = 0; i < 4; ++i) {
            const int chunk = i * 256 + t;
            const int row = chunk >> 3;
            const int c8 = (chunk & 7) * 8;
            const int gr = m0 + row;
            if (gr < M) {
                const short8 v8 =
                    *(const short8*)&lflat[row * 64 + (c8 ^ ((row & 7) << 3))];
                const int gcl = n0 + p * 64 + c8;
                if (EPI == 5) {
                    const int b = gr / LQn, s = gr - b * LQn;
                    const int hh = gcl >> 5, dd = gcl & 31;
                    *(short8*)&((short*)C)[(((size_t)b * 8 + hh) * LQn + s) * 32 + dd] = v8;
                } else {
                    *(short8*)&((short*)C)[(size_t)gr * ldc + gcl] = v8;
                }
            }
        }
        __syncthreads();
    }
}

// ---------------------------------------------------------------------------
// 512-thread 128x256-tile GEMM with fused row-LayerNorm epilogue.
// EPI 0: output = bf16 (bounce). EPI 1: output = fp32 d_out.
// resbf: residual dtype (1 = bf16, 0 = fp32).
// ---------------------------------------------------------------------------
template <int EPI>
__global__ __launch_bounds__(512) void gemm_ln(const short* __restrict__ Ab,
                                               const short* __restrict__ BT,
                                               const float* __restrict__ bias,
                                               const void* __restrict__ resid,
                                               void* __restrict__ out,
                                               const float* __restrict__ g,
                                               const float* __restrict__ be,
                                               int M, int K, int resbf) {
    const int t = threadIdx.x;
    const int m0 = blockIdx.x * 128;
    const int wid = t >> 6, lane = t & 63;
    const int wr = wid >> 2, wc = wid & 3;
    const int quad = lane >> 4, l16 = lane & 15;

    __shared__ short lA[2][128 * 32];
    __shared__ short lB[2][256 * 32];
    __shared__ float2 part[128][4];
    __shared__ float2 stats[128];

    f32x4 acc[4][4];
#pragma unroll
    for (int i = 0; i < 4; ++i)
#pragma unroll
        for (int j = 0; j < 4; ++j) acc[i][j] = (f32x4){0.f, 0.f, 0.f, 0.f};

    const int ga_row = wid * 16 + (lane >> 2);
    const int gb_row = wid * 32 + (lane >> 2);
    const int gcol8 = (lane & 3) * 8;
    auto stage = [&](int buf, int k0) {
        GLOAD16(Ab + (size_t)(m0 + ga_row) * K + k0 + gcol8,
                &lA[buf][(wid * 16) * 32]);
        GLOAD16(BT + (size_t)gb_row * K + k0 + gcol8,
                &lB[buf][(wid * 32) * 32]);
        GLOAD16(BT + (size_t)(gb_row + 16) * K + k0 + gcol8,
                &lB[buf][(wid * 32 + 16) * 32]);
    };
    stage(0, 0);
    __syncthreads();
    int cur = 0;
    for (int k0 = 0; k0 < K; k0 += 32) {
        if (k0 + 32 < K) stage(cur ^ 1, k0 + 32);
        short8 af[4], bfr[4];
#pragma unroll
        for (int mi = 0; mi < 4; ++mi)
            af[mi] = *(const short8*)&lA[cur][(wr * 64 + mi * 16 + l16) * 32 + quad * 8];
#pragma unroll
        for (int ni = 0; ni < 4; ++ni)
            bfr[ni] = *(const short8*)&lB[cur][(wc * 64 + ni * 16 + l16) * 32 + quad * 8];
#pragma unroll
        for (int mi = 0; mi < 4; ++mi)
#pragma unroll
            for (int ni = 0; ni < 4; ++ni)
                acc[mi][ni] = __builtin_amdgcn_mfma_f32_16x16x32_bf16(
                    af[mi], bfr[ni], acc[mi][ni], 0, 0, 0);
        __syncthreads();
        cur ^= 1;
    }

    float biasv[4], gv[4], bev[4];
    int gcs[4];
#pragma unroll
    for (int ni = 0; ni < 4; ++ni) {
        gcs[ni] = wc * 64 + ni * 16 + l16;
        biasv[ni] = bias[gcs[ni]];
        gv[ni] = g[gcs[ni]];
        bev[ni] = be[gcs[ni]];
    }
#pragma unroll
    for (int mi = 0; mi < 4; ++mi) {
#pragma unroll
        for (int r = 0; r < 4; ++r) {
            const int lr = wr * 64 + mi * 16 + quad * 4 + r;
            const int gr = m0 + lr;
            const bool ok = (gr < M);
            float s1 = 0.f, s2 = 0.f;
#pragma unroll
            for (int ni = 0; ni < 4; ++ni) {
                float v = acc[mi][ni][r] + biasv[ni];
                if (ok) {
                    if (resbf)
                        v += bf2f(((const short*)resid)[(size_t)gr * 256 + gcs[ni]]);
                    else
                        v += ((const float*)resid)[(size_t)gr * 256 + gcs[ni]];
                }
                acc[mi][ni][r] = v;
                s1 += v;
                s2 += v * v;
            }
#pragma unroll
            for (int o = 1; o < 16; o <<= 1) {
                s1 += __shfl_xor(s1, o);
                s2 += __shfl_xor(s2, o);
            }
            if (l16 == 0) part[lr][wc] = make_float2(s1, s2);
        }
    }
    __syncthreads();
    if (t < 128) {
        float s1 = 0.f, s2 = 0.f;
#pragma unroll
        for (int w = 0; w < 4; ++w) {
            const float2 p = part[t][w];
            s1 += p.x;
            s2 += p.y;
        }
        const float mean = s1 * (1.0f / 256.0f);
        const float var = s2 * (1.0f / 256.0f) - mean * mean;
        stats[t] = make_float2(mean, rsqrtf(var + 1e-5f));
    }
    __syncthreads();

    if (EPI == 0) {
        short* lflat = (short*)lA;
#pragma unroll
        for (int p = 0; p < 4; ++p) {
            if (wc == p) {
#pragma unroll
                for (int mi = 0; mi < 4; ++mi)
#pragma unroll
                    for (int r = 0; r < 4; ++r) {
                        const int lr = wr * 64 + mi * 16 + quad * 4 + r;
                        const float2 st = stats[lr];
#pragma unroll
                        for (int ni = 0; ni < 4; ++ni) {
                            const int lc = ni * 16 + l16;
                            const float v =
                                (acc[mi][ni][r] - st.x) * st.y * gv[ni] + bev[ni];
                            lflat[lr * 64 + (lc ^ ((lr & 7) << 3))] = f2bf(v);
                        }
                    }
            }
            __syncthreads();
#pragma unroll
            for (int i = 0; i < 2; ++i) {
                const int chunk = i * 512 + t;
                const int row = chunk >> 3;
                const int c8 = (chunk & 7) * 8;
                const int gr = m0 + row;
                if (gr < M) {
                    const short8 v8 =
                        *(const short8*)&lflat[row * 64 + (c8 ^ ((row & 7) << 3))];
                    *(short8*)&((short*)out)[(size_t)gr * 256 + p * 64 + c8] = v8;
                }
            }
            __syncthreads();
        }
    } else {
#pragma unroll
        for (int mi = 0; mi < 4; ++mi) {
#pragma unroll
            for (int r = 0; r < 4; ++r) {
                const int lr = wr * 64 + mi * 16 + quad * 4 + r;
                const int gr = m0 + lr;
                if (gr < M) {
                    const float2 st = stats[lr];
#pragma unroll
                    for (int ni = 0; ni < 4; ++ni) {
                        const float v =
                            (acc[mi][ni][r] - st.x) * st.y * gv[ni] + bev[ni];
                        ((float*)out)[(size_t)gr * 256 + gcs[ni]] = v;
                    }
                }
            }
        }
    }
}

// ---------------------------------------------------------------------------
// MS deformable sampling, head-major value [B][NH][LQ][HD].
// VF32=1: value fp32 (no unpack shifts); VF32=0: value bf16.
// 16 threads per (row, head); cross-level sums via shfl_xor {4,8}.
// ---------------------------------------------------------------------------
template <int VF32>
__global__ __launch_bounds__(256) void sample_k(const void* __restrict__ value,
                                                const short* __restrict__ offaw,
                                                const float* __restrict__ refp,
                                                short* __restrict__ attn,
                                                int nwg) {
    int wg = blockIdx.x;
    {
        const int q = nwg >> 3, r = nwg & 7;
        const int xcd = wg & 7, idx = wg >> 3;
        wg = (xcd < r ? xcd * (q + 1) : r * (q + 1) + (xcd - r) * q) + idx;
    }
    const int tid = threadIdx.x;
    const int grp = wg * 16 + (tid >> 4);
    const int s16 = tid & 15;
    const int l = s16 >> 2, sub = s16 & 3;
    const int row = grp >> 3, h = grp & 7;
    const int b = row / LQn;
    const int L = (l == 0) ? 100 : (l == 1) ? 50 : (l == 2) ? 25 : 13;
    const int O = (l == 0) ? 0 : (l == 1) ? 10000 : (l == 2) ? 12500 : 13125;
    const float Lf = (float)L;

    const short* op = offaw + (size_t)row * 384 + h * 32;
    const short* ap = offaw + (size_t)row * 384 + 256 + h * 16;

    const short4v alog = *(const short4v*)(ap + l * 4);
    float lg[4];
#pragma unroll
    for (int j = 0; j < 4; ++j) lg[j] = bf2f(alog[j]);
    float m = fmaxf(fmaxf(lg[0], lg[1]), fmaxf(lg[2], lg[3]));
    m = fmaxf(m, __shfl_xor(m, 4));
    m = fmaxf(m, __shfl_xor(m, 8));
    float s = 0.f;
#pragma unroll
    for (int j = 0; j < 4; ++j) { lg[j] = __expf(lg[j] - m); s += lg[j]; }
    s += __shfl_xor(s, 4);
    s += __shfl_xor(s, 8);
    const float inv = 1.f / s;

    const float2 rxy = *(const float2*)(refp + (size_t)row * 8 + l * 2);
    const short8 ov = *(const short8*)(op + l * 8);
    const size_t plane = ((size_t)(b * 8 + h) * LQn + O) * 32 + sub * 8;
    const float* vlevf = (const float*)value + plane;
    const short* vlevh = (const short*)value + plane;

    f32x4 accA = (f32x4){0.f, 0.f, 0.f, 0.f};
    f32x4 accB = (f32x4){0.f, 0.f, 0.f, 0.f};

#pragma unroll 2
    for (int p = 0; p < 4; ++p) {
        const float x = fmaf(rxy.x, Lf, bf2f(ov[p * 2 + 0]) - 0.5f);
        const float y = fmaf(rxy.y, Lf, bf2f(ov[p * 2 + 1]) - 0.5f);
        const float xf = floorf(x), yf = floorf(y);
        const int ix = (int)xf, iy = (int)yf;
        const float fx = x - xf, fy = y - yf;
        const float aw = lg[p] * inv;
        const float vx0 = ((unsigned)ix < (unsigned)L) ? 1.f : 0.f;
        const float vx1 = ((unsigned)(ix + 1) < (unsigned)L) ? 1.f : 0.f;
        const float vy0 = ((unsigned)iy < (unsigned)L) ? 1.f : 0.f;
        const float vy1 = ((unsigned)(iy + 1) < (unsigned)L) ? 1.f : 0.f;
        const float gx0 = (1.f - fx) * aw, gx1 = fx * aw;
        const float w00 = gx0 * (1.f - fy) * vx0 * vy0;
        const float w10 = gx1 * (1.f - fy) * vx1 * vy0;
        const float w01 = gx0 * fy * vx0 * vy1;
        const float w11 = gx1 * fy * vx1 * vy1;
        const int ix0 = min(max(ix, 0), L - 1);
        const int ix1 = min(max(ix + 1, 0), L - 1);
        const int iy0 = min(max(iy, 0), L - 1);
        const int iy1 = min(max(iy + 1, 0), L - 1);
        const int ro0 = iy0 * L, ro1 = iy1 * L;
        const int o00 = (ro0 + ix0) << 5, o10 = (ro0 + ix1) << 5;
        const int o01 = (ro1 + ix0) << 5, o11 = (ro1 + ix1) << 5;
        if (VF32) {
            const f32x4 a00 = *(const f32x4*)(vlevf + o00);
            const f32x4 b00 = *(const f32x4*)(vlevf + o00 + 4);
            const f32x4 a10 = *(const f32x4*)(vlevf + o10);
            const f32x4 b10 = *(const f32x4*)(vlevf + o10 + 4);
            const f32x4 a01 = *(const f32x4*)(vlevf + o01);
            const f32x4 b01 = *(const f32x4*)(vlevf + o01 + 4);
            const f32x4 a11 = *(const f32x4*)(vlevf + o11);
            const f32x4 b11 = *(const f32x4*)(vlevf + o11 + 4);
            accA += w00 * a00 + w10 * a10 + w01 * a01 + w11 * a11;
            accB += w00 * b00 + w10 * b10 + w01 * b01 + w11 * b11;
        } else {
            const short8 v00 = *(const short8*)(vlevh + o00);
            const short8 v10 = *(const short8*)(vlevh + o10);
            const short8 v01 = *(const short8*)(vlevh + o01);
            const short8 v11 = *(const short8*)(vlevh + o11);
#pragma unroll
            for (int j = 0; j < 4; ++j) {
                accA[j] += w00 * bf2f(v00[j]) + w10 * bf2f(v10[j]) +
                           w01 * bf2f(v01[j]) + w11 * bf2f(v11[j]);
                accB[j] += w00 * bf2f(v00[j + 4]) + w10 * bf2f(v10[j + 4]) +
                           w01 * bf2f(v01[j + 4]) + w11 * bf2f(v11[j + 4]);
            }
        }
    }

    float acc[8];
#pragma unroll
    for (int j = 0; j < 4; ++j) { acc[j] = accA[j]; acc[j + 4] = accB[j]; }
#pragma unroll
    for (int j = 0; j < 8; ++j) {
        acc[j] += __shfl_xor(acc[j], 4);
        acc[j] += __shfl_xor(acc[j], 8);
    }

    if (l == 0) {
        short8 o;
#pragma unroll
        for (int j = 0; j < 8; ++j) o[j] = f2bf(acc[j]);
        *(short8*)(attn + (size_t)row * 256 + h * 32 + sub * 8) = o;
    }
}

// ---------------------------------------------------------------------------
extern "C" void kernel_launch(void* const* d_in, const int* in_sizes, int n_in,
                              void* d_out, int out_size, void* d_ws, size_t ws_size,
                              hipStream_t stream) {
    (void)in_sizes; (void)n_in; (void)out_size;
    const float* src  = (const float*)d_in[0];
    const float* pos  = (const float*)d_in[1];
    const float* refp = (const float*)d_in[2];
    const float* Wv = (const float*)d_in[5];
    const float* bv = (const float*)d_in[6];
    const float* Ws = (const float*)d_in[7];
    const float* bs = (const float*)d_in[8];
    const float* Wa = (const float*)d_in[9];
    const float* ba = (const float*)d_in[10];
    const float* Wo = (const float*)d_in[11];
    const float* bo = (const float*)d_in[12];
    const float* W1 = (const float*)d_in[13];
    const float* b1 = (const float*)d_in[14];
    const float* W2 = (const float*)d_in[15];
    const float* b2 = (const float*)d_in[16];
    const float* g1 = (const float*)d_in[17];
    const float* be1 = (const float*)d_in[18];
    const float* g2 = (const float*)d_in[19];
    const float* be2 = (const float*)d_in[20];

    char* ws = (char*)d_ws;
    size_t off = 0;
    auto take = [&](size_t bytes) {
        char* p = ws + off;
        off += (bytes + 255) & ~(size_t)255;
        return p;
    };
    short* WvT  = (short*)take(256 * 256 * 2);
    short* WsaT = (short*)take(384 * 256 * 2);
    short* WoT  = (short*)take(256 * 256 * 2);
    short* W1T  = (short*)take(1024 * 256 * 2);
    short* W2T  = (short*)take(256 * 1024 * 2);
    float* bsa  = (float*)take(384 * 4);
    const size_t wbytes = off;

    const size_t SZ_VF = (size_t)MP * 256 * 4;   // fp32 value
    const size_t SZ_VH = (size_t)MP * 256 * 2;   // bf16 value / x_bf / attn / src_bf
    const size_t SZ_OF = (size_t)MP * 384 * 2;   // offaw
    // Config: A = fp32 value + persistent src_bf; B = fp32 value; C = bf16.
    const bool cfgA = wbytes + SZ_VF + SZ_OF + SZ_VH + SZ_VH + 1024 <= ws_size;
    const bool cfgB = !cfgA && wbytes + SZ_VF + SZ_OF + SZ_VH + 1024 <= ws_size;
    const bool f32v = cfgA || cfgB;

    char* value_rg = (char*)take(f32v ? SZ_VF : SZ_VH);  // value; later x_bf
    short* offaw   = (short*)take(SZ_OF);                // later h part 1
    short* attn_bf = (short*)take(SZ_VH);                // q_bf / attn / h part 2
    short* src_bf  = cfgA ? (short*)take(SZ_VH) : offaw; // persistent or transient
    const int resbf_g4 = cfgA ? 1 : 0;

    short* q_bf = attn_bf;
    short* x_bf = (short*)value_rg;
    short* h    = offaw;
    float* z    = (float*)d_out;

    prep_all<<<9593, 256, 0, stream>>>(Wv, Ws, Wa, Wo, W1, W2, bs, ba, src, pos,
                                       WvT, WsaT, WoT, W1T, W2T, bsa, q_bf,
                                       src_bf);
    // G1: value (head-major) = src_bf @ WvT + bv
    if (f32v)
        gemm_bt<6, 2><<<832, 256, 0, stream>>>(
            src_bf, WvT, bv, value_rg, MREAL, 256, 256, 256, 256);
    else
        gemm_bt<5, 2><<<832, 256, 0, stream>>>(
            src_bf, WvT, bv, value_rg, MREAL, 256, 256, 256, 256);
    // G2: offaw = q_bf @ WsaT + bsa
    gemm_bt<1, 3><<<1248, 256, 0, stream>>>(
        q_bf, WsaT, bsa, offaw, MREAL, 256, 384, 256, 384);
    // Deformable sampling
    {
        const int nwg = (MREAL * 8) / 16;  // 26588 blocks
        if (f32v)
            sample_k<1><<<nwg, 256, 0, stream>>>(value_rg, offaw, refp, attn_bf, nwg);
        else
            sample_k<0><<<nwg, 256, 0, stream>>>(value_rg, offaw, refp, attn_bf, nwg);
    }
    // G4 + LN1 fused: x_bf = LN(resid + attn @ WoT + bo)
    gemm_ln<0><<<MT, 512, 0, stream>>>(attn_bf, WoT, bo,
                                       resbf_g4 ? (const void*)src_bf
                                                : (const void*)src,
                                       x_bf, g1, be1, MREAL, 256, resbf_g4);
    // FFN over two M-halves; G6 + LN2 fused
    for (int half = 0; half < 2; ++half) {
        const size_t ro = (size_t)half * MHALF;
        gemm_bt<2, 8><<<1664, 256, 0, stream>>>(
            x_bf + ro * 256, W1T, b1, h, MHALF, 256, 1024, 256, 1024);
        gemm_ln<1><<<MTH, 512, 0, stream>>>(h, W2T, b2, x_bf + ro * 256,
                                            z + ro * 256, g2, be2, MHALF, 1024,
                                            1);
    }
}

// Round 13
// 415.706 us; speedup vs baseline: 1.1729x; 1.1729x over previous
//
#include <hip/hip_runtime.h>

// ---------------------------------------------------------------------------
// DeformableTransformerEncoderLayer on MI355X (gfx950)
// B=4, LQ=13294, DM=256, DFFN=1024, NL=4, NH=8, NP=4, HD=32
// M = 53176 rows, padded tiles to Mp = 53248 = 416*128.
// Round 13: REVERT round-12's fp32 value (FETCH 3x, sample 122->172 µs).
// Back to bf16 head-major value + R11 structure; sample_k inner loop now
// accumulates on f32x2 (v_pk_fma_f32) to halve FMA count.
// Pipeline (9 dispatches):
//   prep_all (+q_bf,+src_bf); G1 value_h; G2 offaw; sample; G4LN x_bf;
//   2x { G5 h; G6LN d_out }
// ---------------------------------------------------------------------------

#define LQn   13294
#define MREAL 53176
#define MP    53248
#define MT    416
#define MHALF 26588
#define MTH   208

typedef __attribute__((ext_vector_type(8))) short short8;
typedef __attribute__((ext_vector_type(4))) short short4v;
typedef __attribute__((ext_vector_type(4))) float f32x4;
typedef __attribute__((ext_vector_type(2))) float f32x2;

__device__ __forceinline__ short f2bf(float f) {
    unsigned u = __float_as_uint(f);
    unsigned r = (u + 0x7FFFu + ((u >> 16) & 1u)) >> 16;  // RNE
    return (short)r;
}
__device__ __forceinline__ float bf2f(short b) {
    return __uint_as_float(((unsigned)(unsigned short)b) << 16);
}
// unpack a 32-bit reg holding 2 bf16 into f32x2 (2 VALU, feeds v_pk_fma_f32)
__device__ __forceinline__ f32x2 bf2x2(unsigned r) {
    f32x2 o;
    o.x = __uint_as_float(r << 16);
    o.y = __uint_as_float(r & 0xffff0000u);
    return o;
}

#define GLOAD16(gp, lp)                                                        \
    __builtin_amdgcn_global_load_lds(                                          \
        (const __attribute__((address_space(1))) void*)(gp),                   \
        (__attribute__((address_space(3))) void*)(lp), 16, 0, 0)

// ---------------------------------------------------------------------------
// Weight prep + bias concat + q_bf / src_bf, all in ONE dispatch.
// ---------------------------------------------------------------------------
__global__ __launch_bounds__(256) void prep_all(
    const float* __restrict__ Wv, const float* __restrict__ Ws,
    const float* __restrict__ Wa, const float* __restrict__ Wo,
    const float* __restrict__ W1, const float* __restrict__ W2,
    const float* __restrict__ bs, const float* __restrict__ ba,
    const float* __restrict__ src, const float* __restrict__ pos,
    short* __restrict__ WvT, short* __restrict__ WsaT,
    short* __restrict__ WoT, short* __restrict__ W1T,
    short* __restrict__ W2T, float* __restrict__ bsa,
    short* __restrict__ q_bf, short* __restrict__ src_bf) {
    const int bid = blockIdx.x, tid = threadIdx.x;
    if (bid >= 2945) {
        const int i = (bid - 2945) * 256 + tid;
        if (i < MREAL * 32) {
            const float4 a0 = ((const float4*)src)[i * 2];
            const float4 a1 = ((const float4*)src)[i * 2 + 1];
            const float4 b0 = ((const float4*)pos)[i * 2];
            const float4 b1 = ((const float4*)pos)[i * 2 + 1];
            short8 o, o2;
            o[0] = f2bf(a0.x + b0.x); o[1] = f2bf(a0.y + b0.y);
            o[2] = f2bf(a0.z + b0.z); o[3] = f2bf(a0.w + b0.w);
            o[4] = f2bf(a1.x + b1.x); o[5] = f2bf(a1.y + b1.y);
            o[6] = f2bf(a1.z + b1.z); o[7] = f2bf(a1.w + b1.w);
            o2[0] = f2bf(a0.x); o2[1] = f2bf(a0.y);
            o2[2] = f2bf(a0.z); o2[3] = f2bf(a0.w);
            o2[4] = f2bf(a1.x); o2[5] = f2bf(a1.y);
            o2[6] = f2bf(a1.z); o2[7] = f2bf(a1.w);
            ((short8*)q_bf)[i] = o;
            ((short8*)src_bf)[i] = o2;
        }
        return;
    }
    const float* W; short* WT; int K, N, base;
    if (bid < 256)       { W = Wv; WT = WvT;              K = 256;  N = 256;  base = 0; }
    else if (bid < 512)  { W = Ws; WT = WsaT;             K = 256;  N = 256;  base = 256; }
    else if (bid < 640)  { W = Wa; WT = WsaT + 256 * 256; K = 256;  N = 128;  base = 512; }
    else if (bid < 896)  { W = Wo; WT = WoT;              K = 256;  N = 256;  base = 640; }
    else if (bid < 1920) { W = W1; WT = W1T;              K = 256;  N = 1024; base = 896; }
    else if (bid < 2944) { W = W2; WT = W2T;              K = 1024; N = 256;  base = 1920; }
    else {
        if (tid < 256) bsa[tid] = bs[tid];
        else if (tid < 384) bsa[tid] = ba[tid - 256];
        return;
    }
    const int i = (bid - base) * 256 + tid;
    const int n = i / K, k = i - n * K;
    WT[i] = f2bf(W[(size_t)k * N + n]);
}

// ---------------------------------------------------------------------------
// bf16 MFMA GEMM. 128x128 tile, BK=32, 4 waves, 16x16x32 MFMA.
// Dbuf global_load_lds staging; NT-swizzled 1-D grid (A-tile L2 locality).
// Vectorized LDS-bounce epilogue (short8 stores).
// EPI: 1 = bf16+bias; 2 = relu->bf16+bias; 5 = bf16+bias head-major scatter
// ---------------------------------------------------------------------------
template <int EPI, int NT>
__global__ __launch_bounds__(256) void gemm_bt(const short* __restrict__ Ab,
                                               const short* __restrict__ BT,
                                               const float* __restrict__ bias,
                                               void* C,
                                               int M, int K, int N,
                                               int ldb, int ldc) {
    const int d = blockIdx.x;
    const int c = d & 7, j = d >> 3;
    const int jg = j / NT;
    const int m0 = (c + 8 * jg) * 128;
    const int n0 = (j - jg * NT) * 128;
    const int t = threadIdx.x;
    const int wid = t >> 6, lane = t & 63;
    const int wr = wid >> 1, wc = wid & 1;
    const int quad = lane >> 4, l16 = lane & 15;

    __shared__ short lA[2][128 * 32];
    __shared__ short lB[2][128 * 32];

    f32x4 acc[4][4];
#pragma unroll
    for (int i = 0; i < 4; ++i)
#pragma unroll
        for (int jj = 0; jj < 4; ++jj) acc[i][jj] = (f32x4){0.f, 0.f, 0.f, 0.f};

    const int grow = wid * 32 + (lane >> 2);
    const int gcol = (lane & 3) * 8;
    auto stage = [&](int buf, int k0) {
        GLOAD16(Ab + (size_t)(m0 + grow) * K + k0 + gcol,
                &lA[buf][(wid * 32) * 32]);
        GLOAD16(Ab + (size_t)(m0 + grow + 16) * K + k0 + gcol,
                &lA[buf][(wid * 32 + 16) * 32]);
        GLOAD16(BT + (size_t)(n0 + grow) * ldb + k0 + gcol,
                &lB[buf][(wid * 32) * 32]);
        GLOAD16(BT + (size_t)(n0 + grow + 16) * ldb + k0 + gcol,
                &lB[buf][(wid * 32 + 16) * 32]);
    };
    stage(0, 0);
    __syncthreads();
    int cur = 0;
    for (int k0 = 0; k0 < K; k0 += 32) {
        if (k0 + 32 < K) stage(cur ^ 1, k0 + 32);
        short8 af[4], bfr[4];
#pragma unroll
        for (int mi = 0; mi < 4; ++mi)
            af[mi] = *(const short8*)&lA[cur][(wr * 64 + mi * 16 + l16) * 32 + quad * 8];
#pragma unroll
        for (int ni = 0; ni < 4; ++ni)
            bfr[ni] = *(const short8*)&lB[cur][(wc * 64 + ni * 16 + l16) * 32 + quad * 8];
#pragma unroll
        for (int mi = 0; mi < 4; ++mi)
#pragma unroll
            for (int ni = 0; ni < 4; ++ni)
                acc[mi][ni] = __builtin_amdgcn_mfma_f32_16x16x32_bf16(
                    af[mi], bfr[ni], acc[mi][ni], 0, 0, 0);
        __syncthreads();
        cur ^= 1;
    }

    // ---- LDS-bounce vectorized epilogue: 2 passes of 64 cols ----
    short* lflat = (short*)lA;  // 8192 shorts = 128 x 64
#pragma unroll
    for (int p = 0; p < 2; ++p) {
        if (wc == p) {
#pragma unroll
            for (int ni = 0; ni < 4; ++ni) {
                const int lc = ni * 16 + l16;
                const float bia = bias[n0 + p * 64 + lc];
#pragma unroll
                for (int mi = 0; mi < 4; ++mi)
#pragma unroll
                    for (int r = 0; r < 4; ++r) {
                        const int lr = wr * 64 + mi * 16 + quad * 4 + r;
                        float v = acc[mi][ni][r] + bia;
                        if (EPI == 2) v = fmaxf(v, 0.f);
                        lflat[lr * 64 + (lc ^ ((lr & 7) << 3))] = f2bf(v);
                    }
            }
        }
        __syncthreads();
#pragma unroll
        for (int i = 0; i < 4; ++i) {
            const int chunk = i * 256 + t;
            const int row = chunk >> 3;
            const int c8 = (chunk & 7) * 8;
            const int gr = m0 + row;
            if (gr < M) {
                const short8 v8 =
                    *(const short8*)&lflat[row * 64 + (c8 ^ ((row & 7) << 3))];
                const int gcl = n0 + p * 64 + c8;
                if (EPI == 5) {
                    const int b = gr / LQn, s = gr - b * LQn;
                    const int hh = gcl >> 5, dd = gcl & 31;
                    *(short8*)&((short*)C)[(((size_t)b * 8 + hh) * LQn + s) * 32 + dd] = v8;
                } else {
                    *(short8*)&((short*)C)[(size_t)gr * ldc + gcl] = v8;
                }
            }
        }
        __syncthreads();
    }
}

// ---------------------------------------------------------------------------
// 512-thread 128x256-tile GEMM with fused row-LayerNorm epilogue.
// EPI 0: output = bf16 (bounce). EPI 1: output = fp32 d_out.
// resbf: residual dtype (1 = bf16, 0 = fp32).
// ---------------------------------------------------------------------------
template <int EPI>
__global__ __launch_bounds__(512) void gemm_ln(const short* __restrict__ Ab,
                                               const short* __restrict__ BT,
                                               const float* __restrict__ bias,
                                               const void* __restrict__ resid,
                                               void* __restrict__ out,
                                               const float* __restrict__ g,
                                               const float* __restrict__ be,
                                               int M, int K, int resbf) {
    const int t = threadIdx.x;
    const int m0 = blockIdx.x * 128;
    const int wid = t >> 6, lane = t & 63;
    const int wr = wid >> 2, wc = wid & 3;
    const int quad = lane >> 4, l16 = lane & 15;

    __shared__ short lA[2][128 * 32];
    __shared__ short lB[2][256 * 32];
    __shared__ float2 part[128][4];
    __shared__ float2 stats[128];

    f32x4 acc[4][4];
#pragma unroll
    for (int i = 0; i < 4; ++i)
#pragma unroll
        for (int j = 0; j < 4; ++j) acc[i][j] = (f32x4){0.f, 0.f, 0.f, 0.f};

    const int ga_row = wid * 16 + (lane >> 2);
    const int gb_row = wid * 32 + (lane >> 2);
    const int gcol8 = (lane & 3) * 8;
    auto stage = [&](int buf, int k0) {
        GLOAD16(Ab + (size_t)(m0 + ga_row) * K + k0 + gcol8,
                &lA[buf][(wid * 16) * 32]);
        GLOAD16(BT + (size_t)gb_row * K + k0 + gcol8,
                &lB[buf][(wid * 32) * 32]);
        GLOAD16(BT + (size_t)(gb_row + 16) * K + k0 + gcol8,
                &lB[buf][(wid * 32 + 16) * 32]);
    };
    stage(0, 0);
    __syncthreads();
    int cur = 0;
    for (int k0 = 0; k0 < K; k0 += 32) {
        if (k0 + 32 < K) stage(cur ^ 1, k0 + 32);
        short8 af[4], bfr[4];
#pragma unroll
        for (int mi = 0; mi < 4; ++mi)
            af[mi] = *(const short8*)&lA[cur][(wr * 64 + mi * 16 + l16) * 32 + quad * 8];
#pragma unroll
        for (int ni = 0; ni < 4; ++ni)
            bfr[ni] = *(const short8*)&lB[cur][(wc * 64 + ni * 16 + l16) * 32 + quad * 8];
#pragma unroll
        for (int mi = 0; mi < 4; ++mi)
#pragma unroll
            for (int ni = 0; ni < 4; ++ni)
                acc[mi][ni] = __builtin_amdgcn_mfma_f32_16x16x32_bf16(
                    af[mi], bfr[ni], acc[mi][ni], 0, 0, 0);
        __syncthreads();
        cur ^= 1;
    }

    float biasv[4], gv[4], bev[4];
    int gcs[4];
#pragma unroll
    for (int ni = 0; ni < 4; ++ni) {
        gcs[ni] = wc * 64 + ni * 16 + l16;
        biasv[ni] = bias[gcs[ni]];
        gv[ni] = g[gcs[ni]];
        bev[ni] = be[gcs[ni]];
    }
#pragma unroll
    for (int mi = 0; mi < 4; ++mi) {
#pragma unroll
        for (int r = 0; r < 4; ++r) {
            const int lr = wr * 64 + mi * 16 + quad * 4 + r;
            const int gr = m0 + lr;
            const bool ok = (gr < M);
            float s1 = 0.f, s2 = 0.f;
#pragma unroll
            for (int ni = 0; ni < 4; ++ni) {
                float v = acc[mi][ni][r] + biasv[ni];
                if (ok) {
                    if (resbf)
                        v += bf2f(((const short*)resid)[(size_t)gr * 256 + gcs[ni]]);
                    else
                        v += ((const float*)resid)[(size_t)gr * 256 + gcs[ni]];
                }
                acc[mi][ni][r] = v;
                s1 += v;
                s2 += v * v;
            }
#pragma unroll
            for (int o = 1; o < 16; o <<= 1) {
                s1 += __shfl_xor(s1, o);
                s2 += __shfl_xor(s2, o);
            }
            if (l16 == 0) part[lr][wc] = make_float2(s1, s2);
        }
    }
    __syncthreads();
    if (t < 128) {
        float s1 = 0.f, s2 = 0.f;
#pragma unroll
        for (int w = 0; w < 4; ++w) {
            const float2 p = part[t][w];
            s1 += p.x;
            s2 += p.y;
        }
        const float mean = s1 * (1.0f / 256.0f);
        const float var = s2 * (1.0f / 256.0f) - mean * mean;
        stats[t] = make_float2(mean, rsqrtf(var + 1e-5f));
    }
    __syncthreads();

    if (EPI == 0) {
        short* lflat = (short*)lA;
#pragma unroll
        for (int p = 0; p < 4; ++p) {
            if (wc == p) {
#pragma unroll
                for (int mi = 0; mi < 4; ++mi)
#pragma unroll
                    for (int r = 0; r < 4; ++r) {
                        const int lr = wr * 64 + mi * 16 + quad * 4 + r;
                        const float2 st = stats[lr];
#pragma unroll
                        for (int ni = 0; ni < 4; ++ni) {
                            const int lc = ni * 16 + l16;
                            const float v =
                                (acc[mi][ni][r] - st.x) * st.y * gv[ni] + bev[ni];
                            lflat[lr * 64 + (lc ^ ((lr & 7) << 3))] = f2bf(v);
                        }
                    }
            }
            __syncthreads();
#pragma unroll
            for (int i = 0; i < 2; ++i) {
                const int chunk = i * 512 + t;
                const int row = chunk >> 3;
                const int c8 = (chunk & 7) * 8;
                const int gr = m0 + row;
                if (gr < M) {
                    const short8 v8 =
                        *(const short8*)&lflat[row * 64 + (c8 ^ ((row & 7) << 3))];
                    *(short8*)&((short*)out)[(size_t)gr * 256 + p * 64 + c8] = v8;
                }
            }
            __syncthreads();
        }
    } else {
#pragma unroll
        for (int mi = 0; mi < 4; ++mi) {
#pragma unroll
            for (int r = 0; r < 4; ++r) {
                const int lr = wr * 64 + mi * 16 + quad * 4 + r;
                const int gr = m0 + lr;
                if (gr < M) {
                    const float2 st = stats[lr];
#pragma unroll
                    for (int ni = 0; ni < 4; ++ni) {
                        const float v =
                            (acc[mi][ni][r] - st.x) * st.y * gv[ni] + bev[ni];
                        ((float*)out)[(size_t)gr * 256 + gcs[ni]] = v;
                    }
                }
            }
        }
    }
}

// ---------------------------------------------------------------------------
// MS deformable sampling, head-major bf16 value [B][NH][LQ][HD].
// 16 threads per (row, head): thread = (level l, dimgroup sub).
// f32x2 packed accumulate (v_pk_fma_f32). Cross-level sums via shfl {4,8}.
// ---------------------------------------------------------------------------
__global__ __launch_bounds__(256) void sample_k(const short* __restrict__ value,
                                                const short* __restrict__ offaw,
                                                const float* __restrict__ refp,
                                                short* __restrict__ attn,
                                                int nwg) {
    int wg = blockIdx.x;
    {
        const int q = nwg >> 3, r = nwg & 7;
        const int xcd = wg & 7, idx = wg >> 3;
        wg = (xcd < r ? xcd * (q + 1) : r * (q + 1) + (xcd - r) * q) + idx;
    }
    const int tid = threadIdx.x;
    const int grp = wg * 16 + (tid >> 4);
    const int s16 = tid & 15;
    const int l = s16 >> 2, sub = s16 & 3;
    const int row = grp >> 3, h = grp & 7;
    const int b = row / LQn;
    const int L = (l == 0) ? 100 : (l == 1) ? 50 : (l == 2) ? 25 : 13;
    const int O = (l == 0) ? 0 : (l == 1) ? 10000 : (l == 2) ? 12500 : 13125;
    const float Lf = (float)L;

    const short* op = offaw + (size_t)row * 384 + h * 32;
    const short* ap = offaw + (size_t)row * 384 + 256 + h * 16;

    const short4v alog = *(const short4v*)(ap + l * 4);
    float lg[4];
#pragma unroll
    for (int j = 0; j < 4; ++j) lg[j] = bf2f(alog[j]);
    float m = fmaxf(fmaxf(lg[0], lg[1]), fmaxf(lg[2], lg[3]));
    m = fmaxf(m, __shfl_xor(m, 4));
    m = fmaxf(m, __shfl_xor(m, 8));
    float s = 0.f;
#pragma unroll
    for (int j = 0; j < 4; ++j) { lg[j] = __expf(lg[j] - m); s += lg[j]; }
    s += __shfl_xor(s, 4);
    s += __shfl_xor(s, 8);
    const float inv = 1.f / s;

    const float2 rxy = *(const float2*)(refp + (size_t)row * 8 + l * 2);
    const short8 ov = *(const short8*)(op + l * 8);
    const short* vlev = value + ((size_t)(b * 8 + h) * LQn + O) * 32 + sub * 8;

    f32x2 acc2[4];
#pragma unroll
    for (int j = 0; j < 4; ++j) acc2[j] = (f32x2){0.f, 0.f};

#pragma unroll 2
    for (int p = 0; p < 4; ++p) {
        const float x = fmaf(rxy.x, Lf, bf2f(ov[p * 2 + 0]) - 0.5f);
        const float y = fmaf(rxy.y, Lf, bf2f(ov[p * 2 + 1]) - 0.5f);
        const float xf = floorf(x), yf = floorf(y);
        const int ix = (int)xf, iy = (int)yf;
        const float fx = x - xf, fy = y - yf;
        const float aw = lg[p] * inv;
        const float vx0 = ((unsigned)ix < (unsigned)L) ? 1.f : 0.f;
        const float vx1 = ((unsigned)(ix + 1) < (unsigned)L) ? 1.f : 0.f;
        const float vy0 = ((unsigned)iy < (unsigned)L) ? 1.f : 0.f;
        const float vy1 = ((unsigned)(iy + 1) < (unsigned)L) ? 1.f : 0.f;
        const float gx0 = (1.f - fx) * aw, gx1 = fx * aw;
        const float w00 = gx0 * (1.f - fy) * vx0 * vy0;
        const float w10 = gx1 * (1.f - fy) * vx1 * vy0;
        const float w01 = gx0 * fy * vx0 * vy1;
        const float w11 = gx1 * fy * vx1 * vy1;
        const int ix0 = min(max(ix, 0), L - 1);
        const int ix1 = min(max(ix + 1, 0), L - 1);
        const int iy0 = min(max(iy, 0), L - 1);
        const int iy1 = min(max(iy + 1, 0), L - 1);
        const int ro0 = iy0 * L, ro1 = iy1 * L;
        const uint4 c00 = *(const uint4*)(vlev + ((ro0 + ix0) << 5));
        const uint4 c10 = *(const uint4*)(vlev + ((ro0 + ix1) << 5));
        const uint4 c01 = *(const uint4*)(vlev + ((ro1 + ix0) << 5));
        const uint4 c11 = *(const uint4*)(vlev + ((ro1 + ix1) << 5));
        const unsigned* p00 = (const unsigned*)&c00;
        const unsigned* p10 = (const unsigned*)&c10;
        const unsigned* p01 = (const unsigned*)&c01;
        const unsigned* p11 = (const unsigned*)&c11;
#pragma unroll
        for (int j = 0; j < 4; ++j)
            acc2[j] += w00 * bf2x2(p00[j]) + w10 * bf2x2(p10[j]) +
                       w01 * bf2x2(p01[j]) + w11 * bf2x2(p11[j]);
    }

    float acc[8];
#pragma unroll
    for (int j = 0; j < 4; ++j) {
        acc[j * 2] = acc2[j].x;
        acc[j * 2 + 1] = acc2[j].y;
    }
#pragma unroll
    for (int j = 0; j < 8; ++j) {
        acc[j] += __shfl_xor(acc[j], 4);
        acc[j] += __shfl_xor(acc[j], 8);
    }

    if (l == 0) {
        short8 o;
#pragma unroll
        for (int j = 0; j < 8; ++j) o[j] = f2bf(acc[j]);
        *(short8*)(attn + (size_t)row * 256 + h * 32 + sub * 8) = o;
    }
}

// ---------------------------------------------------------------------------
extern "C" void kernel_launch(void* const* d_in, const int* in_sizes, int n_in,
                              void* d_out, int out_size, void* d_ws, size_t ws_size,
                              hipStream_t stream) {
    (void)in_sizes; (void)n_in; (void)out_size;
    const float* src  = (const float*)d_in[0];
    const float* pos  = (const float*)d_in[1];
    const float* refp = (const float*)d_in[2];
    const float* Wv = (const float*)d_in[5];
    const float* bv = (const float*)d_in[6];
    const float* Ws = (const float*)d_in[7];
    const float* bs = (const float*)d_in[8];
    const float* Wa = (const float*)d_in[9];
    const float* ba = (const float*)d_in[10];
    const float* Wo = (const float*)d_in[11];
    const float* bo = (const float*)d_in[12];
    const float* W1 = (const float*)d_in[13];
    const float* b1 = (const float*)d_in[14];
    const float* W2 = (const float*)d_in[15];
    const float* b2 = (const float*)d_in[16];
    const float* g1 = (const float*)d_in[17];
    const float* be1 = (const float*)d_in[18];
    const float* g2 = (const float*)d_in[19];
    const float* be2 = (const float*)d_in[20];

    char* ws = (char*)d_ws;
    size_t off = 0;
    auto take = [&](size_t bytes) {
        char* p = ws + off;
        off += (bytes + 255) & ~(size_t)255;
        return p;
    };
    short* WvT  = (short*)take(256 * 256 * 2);
    short* WsaT = (short*)take(384 * 256 * 2);
    short* WoT  = (short*)take(256 * 256 * 2);
    short* W1T  = (short*)take(1024 * 256 * 2);
    short* W2T  = (short*)take(256 * 1024 * 2);
    float* bsa  = (float*)take(384 * 4);
    short* value_h = (short*)take((size_t)MP * 256 * 2);  // later x_bf
    short* offaw   = (short*)take((size_t)MP * 384 * 2);  // later h part 1
    short* attn_bf = (short*)take((size_t)MP * 256 * 2);  // q_bf / attn / h part 2
    // base total ~96.9 MB; optional persistent src_bf below

    short* src_bf;
    int resbf_g4;
    if (off + (size_t)MP * 256 * 2 <= ws_size) {
        src_bf = (short*)take((size_t)MP * 256 * 2);  // persistent; G4 resid bf16
        resbf_g4 = 1;
    } else {
        src_bf = offaw;  // transient (G2 overwrites after G1); G4 resid fp32
        resbf_g4 = 0;
    }

    short* q_bf = attn_bf;
    short* x_bf = value_h;
    short* h    = offaw;
    float* z    = (float*)d_out;

    prep_all<<<9593, 256, 0, stream>>>(Wv, Ws, Wa, Wo, W1, W2, bs, ba, src, pos,
                                       WvT, WsaT, WoT, W1T, W2T, bsa, q_bf,
                                       src_bf);
    // G1: value (head-major) = src_bf @ WvT + bv   (NT=2, 832 blocks)
    gemm_bt<5, 2><<<832, 256, 0, stream>>>(
        src_bf, WvT, bv, value_h, MREAL, 256, 256, 256, 256);
    // G2: offaw = q_bf @ WsaT + bsa                (NT=3, 1248 blocks)
    gemm_bt<1, 3><<<1248, 256, 0, stream>>>(
        q_bf, WsaT, bsa, offaw, MREAL, 256, 384, 256, 384);
    // Deformable sampling
    {
        const int nwg = (MREAL * 8) / 16;  // 26588 blocks
        sample_k<<<nwg, 256, 0, stream>>>(value_h, offaw, refp, attn_bf, nwg);
    }
    // G4 + LN1 fused: x_bf = LN(resid + attn @ WoT + bo)
    gemm_ln<0><<<MT, 512, 0, stream>>>(attn_bf, WoT, bo,
                                       resbf_g4 ? (const void*)src_bf
                                                : (const void*)src,
                                       x_bf, g1, be1, MREAL, 256, resbf_g4);
    // FFN over two M-halves; G6 + LN2 fused
    for (int half = 0; half < 2; ++half) {
        const size_t ro = (size_t)half * MHALF;
        gemm_bt<2, 8><<<1664, 256, 0, stream>>>(
            x_bf + ro * 256, W1T, b1, h, MHALF, 256, 1024, 256, 1024);
        gemm_ln<1><<<MTH, 512, 0, stream>>>(h, W2T, b2, x_bf + ro * 256,
                                            z + ro * 256, g2, be2, MHALF, 1024,
                                            1);
    }
}

// Round 14
// 366.352 us; speedup vs baseline: 1.3309x; 1.1347x over previous
//
#include <hip/hip_runtime.h>

// ---------------------------------------------------------------------------
// DeformableTransformerEncoderLayer on MI355X (gfx950)
// B=4, LQ=13294, DM=256, DFFN=1024, NL=4, NH=8, NP=4, HD=32
// M = 53176 rows, padded tiles to Mp = 53248 = 416*128.
// Round 14:
//  - gemm_ln retiled to 64x256 (832 blocks, 3 blocks/CU -> full CU coverage;
//    R13's 128x256 at 208-block half-dispatches used only 104/256 CUs).
//  - G1+G2 merged into one dispatch (gemm12 -> shared gemm_body).
//  - Full-M FFN when workspace allows (h=109MB overlay, gated; else halves).
// Pipeline (7-8 dispatches):
//   prep_all; gemm12 (G1+G2); sample; G4LN(64-tile); G5; G6LN(64-tile)
// ---------------------------------------------------------------------------

#define LQn   13294
#define MREAL 53176
#define MP    53248
#define MHALF 26588

typedef __attribute__((ext_vector_type(8))) short short8;
typedef __attribute__((ext_vector_type(4))) short short4v;
typedef __attribute__((ext_vector_type(4))) float f32x4;
typedef __attribute__((ext_vector_type(2))) float f32x2;

__device__ __forceinline__ short f2bf(float f) {
    unsigned u = __float_as_uint(f);
    unsigned r = (u + 0x7FFFu + ((u >> 16) & 1u)) >> 16;  // RNE
    return (short)r;
}
__device__ __forceinline__ float bf2f(short b) {
    return __uint_as_float(((unsigned)(unsigned short)b) << 16);
}
__device__ __forceinline__ f32x2 bf2x2(unsigned r) {
    f32x2 o;
    o.x = __uint_as_float(r << 16);
    o.y = __uint_as_float(r & 0xffff0000u);
    return o;
}

#define GLOAD16(gp, lp)                                                        \
    __builtin_amdgcn_global_load_lds(                                          \
        (const __attribute__((address_space(1))) void*)(gp),                   \
        (__attribute__((address_space(3))) void*)(lp), 16, 0, 0)

// ---------------------------------------------------------------------------
// Weight prep + bias concat + q_bf / src_bf, all in ONE dispatch.
// ---------------------------------------------------------------------------
__global__ __launch_bounds__(256) void prep_all(
    const float* __restrict__ Wv, const float* __restrict__ Ws,
    const float* __restrict__ Wa, const float* __restrict__ Wo,
    const float* __restrict__ W1, const float* __restrict__ W2,
    const float* __restrict__ bs, const float* __restrict__ ba,
    const float* __restrict__ src, const float* __restrict__ pos,
    short* __restrict__ WvT, short* __restrict__ WsaT,
    short* __restrict__ WoT, short* __restrict__ W1T,
    short* __restrict__ W2T, float* __restrict__ bsa,
    short* __restrict__ q_bf, short* __restrict__ src_bf) {
    const int bid = blockIdx.x, tid = threadIdx.x;
    if (bid >= 2945) {
        const int i = (bid - 2945) * 256 + tid;
        if (i < MREAL * 32) {
            const float4 a0 = ((const float4*)src)[i * 2];
            const float4 a1 = ((const float4*)src)[i * 2 + 1];
            const float4 b0 = ((const float4*)pos)[i * 2];
            const float4 b1 = ((const float4*)pos)[i * 2 + 1];
            short8 o, o2;
            o[0] = f2bf(a0.x + b0.x); o[1] = f2bf(a0.y + b0.y);
            o[2] = f2bf(a0.z + b0.z); o[3] = f2bf(a0.w + b0.w);
            o[4] = f2bf(a1.x + b1.x); o[5] = f2bf(a1.y + b1.y);
            o[6] = f2bf(a1.z + b1.z); o[7] = f2bf(a1.w + b1.w);
            o2[0] = f2bf(a0.x); o2[1] = f2bf(a0.y);
            o2[2] = f2bf(a0.z); o2[3] = f2bf(a0.w);
            o2[4] = f2bf(a1.x); o2[5] = f2bf(a1.y);
            o2[6] = f2bf(a1.z); o2[7] = f2bf(a1.w);
            ((short8*)q_bf)[i] = o;
            ((short8*)src_bf)[i] = o2;
        }
        return;
    }
    const float* W; short* WT; int K, N, base;
    if (bid < 256)       { W = Wv; WT = WvT;              K = 256;  N = 256;  base = 0; }
    else if (bid < 512)  { W = Ws; WT = WsaT;             K = 256;  N = 256;  base = 256; }
    else if (bid < 640)  { W = Wa; WT = WsaT + 256 * 256; K = 256;  N = 128;  base = 512; }
    else if (bid < 896)  { W = Wo; WT = WoT;              K = 256;  N = 256;  base = 640; }
    else if (bid < 1920) { W = W1; WT = W1T;              K = 256;  N = 1024; base = 896; }
    else if (bid < 2944) { W = W2; WT = W2T;              K = 1024; N = 256;  base = 1920; }
    else {
        if (tid < 256) bsa[tid] = bs[tid];
        else if (tid < 384) bsa[tid] = ba[tid - 256];
        return;
    }
    const int i = (bid - base) * 256 + tid;
    const int n = i / K, k = i - n * K;
    WT[i] = f2bf(W[(size_t)k * N + n]);
}

// ---------------------------------------------------------------------------
// bf16 MFMA GEMM body. 128x128 tile, BK=32, 4 waves, 16x16x32 MFMA.
// Dbuf global_load_lds staging; NT-swizzled block id d.
// lA/lB: caller-provided LDS, each 2*128*32 shorts.
// EPI: 1 = bf16+bias; 2 = relu->bf16+bias; 5 = bf16+bias head-major scatter
// ---------------------------------------------------------------------------
template <int EPI, int NT>
__device__ __forceinline__ void gemm_body(short* lA, short* lB,
                                          const short* __restrict__ Ab,
                                          const short* __restrict__ BT,
                                          const float* __restrict__ bias,
                                          void* C, int d,
                                          int M, int K, int N,
                                          int ldb, int ldc) {
    const int c = d & 7, j = d >> 3;
    const int jg = j / NT;
    const int m0 = (c + 8 * jg) * 128;
    const int n0 = (j - jg * NT) * 128;
    const int t = threadIdx.x;
    const int wid = t >> 6, lane = t & 63;
    const int wr = wid >> 1, wc = wid & 1;
    const int quad = lane >> 4, l16 = lane & 15;

    f32x4 acc[4][4];
#pragma unroll
    for (int i = 0; i < 4; ++i)
#pragma unroll
        for (int jj = 0; jj < 4; ++jj) acc[i][jj] = (f32x4){0.f, 0.f, 0.f, 0.f};

    const int grow = wid * 32 + (lane >> 2);
    const int gcol = (lane & 3) * 8;
    auto stage = [&](int buf, int k0) {
        GLOAD16(Ab + (size_t)(m0 + grow) * K + k0 + gcol,
                &lA[buf * 4096 + (wid * 32) * 32]);
        GLOAD16(Ab + (size_t)(m0 + grow + 16) * K + k0 + gcol,
                &lA[buf * 4096 + (wid * 32 + 16) * 32]);
        GLOAD16(BT + (size_t)(n0 + grow) * ldb + k0 + gcol,
                &lB[buf * 4096 + (wid * 32) * 32]);
        GLOAD16(BT + (size_t)(n0 + grow + 16) * ldb + k0 + gcol,
                &lB[buf * 4096 + (wid * 32 + 16) * 32]);
    };
    stage(0, 0);
    __syncthreads();
    int cur = 0;
    for (int k0 = 0; k0 < K; k0 += 32) {
        if (k0 + 32 < K) stage(cur ^ 1, k0 + 32);
        short8 af[4], bfr[4];
#pragma unroll
        for (int mi = 0; mi < 4; ++mi)
            af[mi] = *(const short8*)&lA[cur * 4096 + (wr * 64 + mi * 16 + l16) * 32 + quad * 8];
#pragma unroll
        for (int ni = 0; ni < 4; ++ni)
            bfr[ni] = *(const short8*)&lB[cur * 4096 + (wc * 64 + ni * 16 + l16) * 32 + quad * 8];
#pragma unroll
        for (int mi = 0; mi < 4; ++mi)
#pragma unroll
            for (int ni = 0; ni < 4; ++ni)
                acc[mi][ni] = __builtin_amdgcn_mfma_f32_16x16x32_bf16(
                    af[mi], bfr[ni], acc[mi][ni], 0, 0, 0);
        __syncthreads();
        cur ^= 1;
    }

    // ---- LDS-bounce vectorized epilogue: 2 passes of 64 cols ----
    short* lflat = lA;  // 8192 shorts = 128 x 64
#pragma unroll
    for (int p = 0; p < 2; ++p) {
        if (wc == p) {
#pragma unroll
            for (int ni = 0; ni < 4; ++ni) {
                const int lc = ni * 16 + l16;
                const float bia = bias[n0 + p * 64 + lc];
#pragma unroll
                for (int mi = 0; mi < 4; ++mi)
#pragma unroll
                    for (int r = 0; r < 4; ++r) {
                        const int lr = wr * 64 + mi * 16 + quad * 4 + r;
                        float v = acc[mi][ni][r] + bia;
                        if (EPI == 2) v = fmaxf(v, 0.f);
                        lflat[lr * 64 + (lc ^ ((lr & 7) << 3))] = f2bf(v);
                    }
            }
        }
        __syncthreads();
#pragma unroll
        for (int i = 0; i < 4; ++i) {
            const int chunk = i * 256 + t;
            const int row = chunk >> 3;
            const int c8 = (chunk & 7) * 8;
            const int gr = m0 + row;
            if (gr < M) {
                const short8 v8 =
                    *(const short8*)&lflat[row * 64 + (c8 ^ ((row & 7) << 3))];
                const int gcl = n0 + p * 64 + c8;
                if (EPI == 5) {
                    const int b = gr / LQn, s = gr - b * LQn;
                    const int hh = gcl >> 5, dd = gcl & 31;
                    *(short8*)&((short*)C)[(((size_t)b * 8 + hh) * LQn + s) * 32 + dd] = v8;
                } else {
                    *(short8*)&((short*)C)[(size_t)gr * ldc + gcl] = v8;
                }
            }
        }
        __syncthreads();
    }
}

template <int EPI, int NT>
__global__ __launch_bounds__(256) void gemm_bt(const short* __restrict__ Ab,
                                               const short* __restrict__ BT,
                                               const float* __restrict__ bias,
                                               void* C, int M, int K, int N,
                                               int ldb, int ldc) {
    __shared__ short sA[2 * 128 * 32];
    __shared__ short sB[2 * 128 * 32];
    gemm_body<EPI, NT>(sA, sB, Ab, BT, bias, C, blockIdx.x, M, K, N, ldb, ldc);
}

// G1 (blocks [0,832)) and G2 (blocks [832,2080)) in one dispatch.
__global__ __launch_bounds__(256) void gemm12(const short* __restrict__ src_bf,
                                              const short* __restrict__ WvT,
                                              const float* __restrict__ bv,
                                              short* __restrict__ value_h,
                                              const short* __restrict__ q_bf,
                                              const short* __restrict__ WsaT,
                                              const float* __restrict__ bsa,
                                              short* __restrict__ offaw) {
    __shared__ short sA[2 * 128 * 32];
    __shared__ short sB[2 * 128 * 32];
    if (blockIdx.x < 832)
        gemm_body<5, 2>(sA, sB, src_bf, WvT, bv, value_h, blockIdx.x,
                        MREAL, 256, 256, 256, 256);
    else
        gemm_body<1, 3>(sA, sB, q_bf, WsaT, bsa, offaw, blockIdx.x - 832,
                        MREAL, 256, 384, 256, 384);
}

// ---------------------------------------------------------------------------
// 512-thread 64x256-tile GEMM with fused row-LayerNorm epilogue.
// 8 waves = 2 row-bands x 4 col-bands; acc[2][4]. ~43 KB LDS -> 3 blocks/CU.
// EPI 0: output = bf16 (bounce). EPI 1: output = fp32.
// resbf: residual dtype (1 = bf16, 0 = fp32). N = 256 fixed, ldc = 256.
// ---------------------------------------------------------------------------
template <int EPI>
__global__ __launch_bounds__(512) void gemm_ln(const short* __restrict__ Ab,
                                               const short* __restrict__ BT,
                                               const float* __restrict__ bias,
                                               const void* __restrict__ resid,
                                               void* __restrict__ out,
                                               const float* __restrict__ g,
                                               const float* __restrict__ be,
                                               int M, int K, int resbf) {
    const int t = threadIdx.x;
    const int m0 = blockIdx.x * 64;
    const int wid = t >> 6, lane = t & 63;
    const int wr = wid >> 2, wc = wid & 3;
    const int quad = lane >> 4, l16 = lane & 15;

    __shared__ short lA[2][64 * 32];
    __shared__ short lB[2][256 * 32];
    __shared__ float2 part[64][4];
    __shared__ float2 stats[64];

    f32x4 acc[2][4];
#pragma unroll
    for (int i = 0; i < 2; ++i)
#pragma unroll
        for (int j = 0; j < 4; ++j) acc[i][j] = (f32x4){0.f, 0.f, 0.f, 0.f};

    const int gb_row = wid * 32 + (lane >> 2);
    const int gcol8 = (lane & 3) * 8;
    auto stage = [&](int buf, int k0) {
        if (wid < 4)
            GLOAD16(Ab + (size_t)(m0 + wid * 16 + (lane >> 2)) * K + k0 + gcol8,
                    &lA[buf][(wid * 16) * 32]);
        GLOAD16(BT + (size_t)gb_row * K + k0 + gcol8,
                &lB[buf][(wid * 32) * 32]);
        GLOAD16(BT + (size_t)(gb_row + 16) * K + k0 + gcol8,
                &lB[buf][(wid * 32 + 16) * 32]);
    };
    stage(0, 0);
    __syncthreads();
    int cur = 0;
    for (int k0 = 0; k0 < K; k0 += 32) {
        if (k0 + 32 < K) stage(cur ^ 1, k0 + 32);
        short8 af[2], bfr[4];
#pragma unroll
        for (int mi = 0; mi < 2; ++mi)
            af[mi] = *(const short8*)&lA[cur][(wr * 32 + mi * 16 + l16) * 32 + quad * 8];
#pragma unroll
        for (int ni = 0; ni < 4; ++ni)
            bfr[ni] = *(const short8*)&lB[cur][(wc * 64 + ni * 16 + l16) * 32 + quad * 8];
#pragma unroll
        for (int mi = 0; mi < 2; ++mi)
#pragma unroll
            for (int ni = 0; ni < 4; ++ni)
                acc[mi][ni] = __builtin_amdgcn_mfma_f32_16x16x32_bf16(
                    af[mi], bfr[ni], acc[mi][ni], 0, 0, 0);
        __syncthreads();
        cur ^= 1;
    }

    float biasv[4], gv[4], bev[4];
    int gcs[4];
#pragma unroll
    for (int ni = 0; ni < 4; ++ni) {
        gcs[ni] = wc * 64 + ni * 16 + l16;
        biasv[ni] = bias[gcs[ni]];
        gv[ni] = g[gcs[ni]];
        bev[ni] = be[gcs[ni]];
    }
#pragma unroll
    for (int mi = 0; mi < 2; ++mi) {
#pragma unroll
        for (int r = 0; r < 4; ++r) {
            const int lr = wr * 32 + mi * 16 + quad * 4 + r;
            const int gr = m0 + lr;
            const bool ok = (gr < M);
            float s1 = 0.f, s2 = 0.f;
#pragma unroll
            for (int ni = 0; ni < 4; ++ni) {
                float v = acc[mi][ni][r] + biasv[ni];
                if (ok) {
                    if (resbf)
                        v += bf2f(((const short*)resid)[(size_t)gr * 256 + gcs[ni]]);
                    else
                        v += ((const float*)resid)[(size_t)gr * 256 + gcs[ni]];
                }
                acc[mi][ni][r] = v;
                s1 += v;
                s2 += v * v;
            }
#pragma unroll
            for (int o = 1; o < 16; o <<= 1) {
                s1 += __shfl_xor(s1, o);
                s2 += __shfl_xor(s2, o);
            }
            if (l16 == 0) part[lr][wc] = make_float2(s1, s2);
        }
    }
    __syncthreads();
    if (t < 64) {
        float s1 = 0.f, s2 = 0.f;
#pragma unroll
        for (int w = 0; w < 4; ++w) {
            const float2 p = part[t][w];
            s1 += p.x;
            s2 += p.y;
        }
        const float mean = s1 * (1.0f / 256.0f);
        const float var = s2 * (1.0f / 256.0f) - mean * mean;
        stats[t] = make_float2(mean, rsqrtf(var + 1e-5f));
    }
    __syncthreads();

    if (EPI == 0) {
        short* lflat = (short*)lA;  // 4096 shorts = 64 x 64
#pragma unroll
        for (int p = 0; p < 4; ++p) {
            if (wc == p) {
#pragma unroll
                for (int mi = 0; mi < 2; ++mi)
#pragma unroll
                    for (int r = 0; r < 4; ++r) {
                        const int lr = wr * 32 + mi * 16 + quad * 4 + r;
                        const float2 st = stats[lr];
#pragma unroll
                        for (int ni = 0; ni < 4; ++ni) {
                            const int lc = ni * 16 + l16;
                            const float v =
                                (acc[mi][ni][r] - st.x) * st.y * gv[ni] + bev[ni];
                            lflat[lr * 64 + (lc ^ ((lr & 7) << 3))] = f2bf(v);
                        }
                    }
            }
            __syncthreads();
            {
                const int row = t >> 3;
                const int c8 = (t & 7) * 8;
                const int gr = m0 + row;
                if (gr < M) {
                    const short8 v8 =
                        *(const short8*)&lflat[row * 64 + (c8 ^ ((row & 7) << 3))];
                    *(short8*)&((short*)out)[(size_t)gr * 256 + p * 64 + c8] = v8;
                }
            }
            __syncthreads();
        }
    } else {
#pragma unroll
        for (int mi = 0; mi < 2; ++mi) {
#pragma unroll
            for (int r = 0; r < 4; ++r) {
                const int lr = wr * 32 + mi * 16 + quad * 4 + r;
                const int gr = m0 + lr;
                if (gr < M) {
                    const float2 st = stats[lr];
#pragma unroll
                    for (int ni = 0; ni < 4; ++ni) {
                        const float v =
                            (acc[mi][ni][r] - st.x) * st.y * gv[ni] + bev[ni];
                        ((float*)out)[(size_t)gr * 256 + gcs[ni]] = v;
                    }
                }
            }
        }
    }
}

// ---------------------------------------------------------------------------
// MS deformable sampling, head-major bf16 value [B][NH][LQ][HD].
// 16 threads per (row, head); f32x2 packed accumulate; shfl {4,8} reduce.
// ---------------------------------------------------------------------------
__global__ __launch_bounds__(256) void sample_k(const short* __restrict__ value,
                                                const short* __restrict__ offaw,
                                                const float* __restrict__ refp,
                                                short* __restrict__ attn,
                                                int nwg) {
    int wg = blockIdx.x;
    {
        const int q = nwg >> 3, r = nwg & 7;
        const int xcd = wg & 7, idx = wg >> 3;
        wg = (xcd < r ? xcd * (q + 1) : r * (q + 1) + (xcd - r) * q) + idx;
    }
    const int tid = threadIdx.x;
    const int grp = wg * 16 + (tid >> 4);
    const int s16 = tid & 15;
    const int l = s16 >> 2, sub = s16 & 3;
    const int row = grp >> 3, h = grp & 7;
    const int b = row / LQn;
    const int L = (l == 0) ? 100 : (l == 1) ? 50 : (l == 2) ? 25 : 13;
    const int O = (l == 0) ? 0 : (l == 1) ? 10000 : (l == 2) ? 12500 : 13125;
    const float Lf = (float)L;

    const short* op = offaw + (size_t)row * 384 + h * 32;
    const short* ap = offaw + (size_t)row * 384 + 256 + h * 16;

    const short4v alog = *(const short4v*)(ap + l * 4);
    float lg[4];
#pragma unroll
    for (int j = 0; j < 4; ++j) lg[j] = bf2f(alog[j]);
    float m = fmaxf(fmaxf(lg[0], lg[1]), fmaxf(lg[2], lg[3]));
    m = fmaxf(m, __shfl_xor(m, 4));
    m = fmaxf(m, __shfl_xor(m, 8));
    float s = 0.f;
#pragma unroll
    for (int j = 0; j < 4; ++j) { lg[j] = __expf(lg[j] - m); s += lg[j]; }
    s += __shfl_xor(s, 4);
    s += __shfl_xor(s, 8);
    const float inv = 1.f / s;

    const float2 rxy = *(const float2*)(refp + (size_t)row * 8 + l * 2);
    const short8 ov = *(const short8*)(op + l * 8);
    const short* vlev = value + ((size_t)(b * 8 + h) * LQn + O) * 32 + sub * 8;

    f32x2 acc2[4];
#pragma unroll
    for (int j = 0; j < 4; ++j) acc2[j] = (f32x2){0.f, 0.f};

#pragma unroll 2
    for (int p = 0; p < 4; ++p) {
        const float x = fmaf(rxy.x, Lf, bf2f(ov[p * 2 + 0]) - 0.5f);
        const float y = fmaf(rxy.y, Lf, bf2f(ov[p * 2 + 1]) - 0.5f);
        const float xf = floorf(x), yf = floorf(y);
        const int ix = (int)xf, iy = (int)yf;
        const float fx = x - xf, fy = y - yf;
        const float aw = lg[p] * inv;
        const float vx0 = ((unsigned)ix < (unsigned)L) ? 1.f : 0.f;
        const float vx1 = ((unsigned)(ix + 1) < (unsigned)L) ? 1.f : 0.f;
        const float vy0 = ((unsigned)iy < (unsigned)L) ? 1.f : 0.f;
        const float vy1 = ((unsigned)(iy + 1) < (unsigned)L) ? 1.f : 0.f;
        const float gx0 = (1.f - fx) * aw, gx1 = fx * aw;
        const float w00 = gx0 * (1.f - fy) * vx0 * vy0;
        const float w10 = gx1 * (1.f - fy) * vx1 * vy0;
        const float w01 = gx0 * fy * vx0 * vy1;
        const float w11 = gx1 * fy * vx1 * vy1;
        const int ix0 = min(max(ix, 0), L - 1);
        const int ix1 = min(max(ix + 1, 0), L - 1);
        const int iy0 = min(max(iy, 0), L - 1);
        const int iy1 = min(max(iy + 1, 0), L - 1);
        const int ro0 = iy0 * L, ro1 = iy1 * L;
        const uint4 c00 = *(const uint4*)(vlev + ((ro0 + ix0) << 5));
        const uint4 c10 = *(const uint4*)(vlev + ((ro0 + ix1) << 5));
        const uint4 c01 = *(const uint4*)(vlev + ((ro1 + ix0) << 5));
        const uint4 c11 = *(const uint4*)(vlev + ((ro1 + ix1) << 5));
        const unsigned* p00 = (const unsigned*)&c00;
        const unsigned* p10 = (const unsigned*)&c10;
        const unsigned* p01 = (const unsigned*)&c01;
        const unsigned* p11 = (const unsigned*)&c11;
#pragma unroll
        for (int j = 0; j < 4; ++j)
            acc2[j] += w00 * bf2x2(p00[j]) + w10 * bf2x2(p10[j]) +
                       w01 * bf2x2(p01[j]) + w11 * bf2x2(p11[j]);
    }

    float acc[8];
#pragma unroll
    for (int j = 0; j < 4; ++j) {
        acc[j * 2] = acc2[j].x;
        acc[j * 2 + 1] = acc2[j].y;
    }
#pragma unroll
    for (int j = 0; j < 8; ++j) {
        acc[j] += __shfl_xor(acc[j], 4);
        acc[j] += __shfl_xor(acc[j], 8);
    }

    if (l == 0) {
        short8 o;
#pragma unroll
        for (int j = 0; j < 8; ++j) o[j] = f2bf(acc[j]);
        *(short8*)(attn + (size_t)row * 256 + h * 32 + sub * 8) = o;
    }
}

// ---------------------------------------------------------------------------
extern "C" void kernel_launch(void* const* d_in, const int* in_sizes, int n_in,
                              void* d_out, int out_size, void* d_ws, size_t ws_size,
                              hipStream_t stream) {
    (void)in_sizes; (void)n_in; (void)out_size;
    const float* src  = (const float*)d_in[0];
    const float* pos  = (const float*)d_in[1];
    const float* refp = (const float*)d_in[2];
    const float* Wv = (const float*)d_in[5];
    const float* bv = (const float*)d_in[6];
    const float* Ws = (const float*)d_in[7];
    const float* bs = (const float*)d_in[8];
    const float* Wa = (const float*)d_in[9];
    const float* ba = (const float*)d_in[10];
    const float* Wo = (const float*)d_in[11];
    const float* bo = (const float*)d_in[12];
    const float* W1 = (const float*)d_in[13];
    const float* b1 = (const float*)d_in[14];
    const float* W2 = (const float*)d_in[15];
    const float* b2 = (const float*)d_in[16];
    const float* g1 = (const float*)d_in[17];
    const float* be1 = (const float*)d_in[18];
    const float* g2 = (const float*)d_in[19];
    const float* be2 = (const float*)d_in[20];

    char* ws = (char*)d_ws;
    size_t off = 0;
    auto take = [&](size_t bytes) {
        char* p = ws + off;
        off += (bytes + 255) & ~(size_t)255;
        return p;
    };
    short* WvT  = (short*)take(256 * 256 * 2);
    short* WsaT = (short*)take(384 * 256 * 2);
    short* WoT  = (short*)take(256 * 256 * 2);
    short* W1T  = (short*)take(1024 * 256 * 2);
    short* W2T  = (short*)take(256 * 1024 * 2);
    float* bsa  = (float*)take(384 * 4);

    const size_t SZ_VH = (size_t)MP * 256 * 2;                  // 27.3 MB
    const size_t SZ_OF = (size_t)MP * 384 * 2;                  // 40.9 MB
    const size_t SZ_H  = (size_t)MP * 1024 * 2;                 // 109.1 MB
    const size_t SZ_HX = SZ_H - (SZ_OF + 2 * SZ_VH);            // 13.6 MB tail

    short* value_h = (short*)take(SZ_VH);  // later x_bf
    short* offaw   = (short*)take(SZ_OF);  // later h (start)
    short* attn_bf = (short*)take(SZ_VH);  // q_bf / attn / h span

    const size_t rem = (off <= ws_size) ? ws_size - off : 0;
    const bool cfgFull = rem >= SZ_VH + SZ_HX + 512;   // src_bf + h tail
    const bool cfgA    = !cfgFull && rem >= SZ_VH + 256;
    short* src_bf;
    int resbf_g4;
    if (cfgFull) {
        src_bf = (short*)take(SZ_VH);
        (void)take(SZ_HX);                 // h tail extension
        resbf_g4 = 1;
    } else if (cfgA) {
        src_bf = (short*)take(SZ_VH);
        resbf_g4 = 1;
    } else {
        src_bf = offaw;                    // transient
        resbf_g4 = 0;
    }

    short* q_bf = attn_bf;
    short* x_bf = value_h;
    short* h    = offaw;   // halves: spans offaw+attn; full: +src_bf+tail
    float* z    = (float*)d_out;

    prep_all<<<9593, 256, 0, stream>>>(Wv, Ws, Wa, Wo, W1, W2, bs, ba, src, pos,
                                       WvT, WsaT, WoT, W1T, W2T, bsa, q_bf,
                                       src_bf);
    // G1 + G2 in one dispatch
    gemm12<<<2080, 256, 0, stream>>>(src_bf, WvT, bv, value_h,
                                     q_bf, WsaT, bsa, offaw);
    // Deformable sampling
    {
        const int nwg = (MREAL * 8) / 16;  // 26588 blocks
        sample_k<<<nwg, 256, 0, stream>>>(value_h, offaw, refp, attn_bf, nwg);
    }
    // G4 + LN1 fused: x_bf = LN(resid + attn @ WoT + bo)   (64-row tiles)
    gemm_ln<0><<<MP / 64, 512, 0, stream>>>(attn_bf, WoT, bo,
                                            resbf_g4 ? (const void*)src_bf
                                                     : (const void*)src,
                                            x_bf, g1, be1, MREAL, 256, resbf_g4);
    if (cfgFull) {
        // FFN full-M: G5 then G6+LN2
        gemm_bt<2, 8><<<3328, 256, 0, stream>>>(
            x_bf, W1T, b1, h, MREAL, 256, 1024, 256, 1024);
        gemm_ln<1><<<MP / 64, 512, 0, stream>>>(h, W2T, b2, x_bf, z, g2, be2,
                                                MREAL, 1024, 1);
    } else {
        for (int half = 0; half < 2; ++half) {
            const size_t ro = (size_t)half * MHALF;
            gemm_bt<2, 8><<<1664, 256, 0, stream>>>(
                x_bf + ro * 256, W1T, b1, h, MHALF, 256, 1024, 256, 1024);
            gemm_ln<1><<<(MHALF + 63) / 64, 512, 0, stream>>>(
                h, W2T, b2, x_bf + ro * 256, z + ro * 256, g2, be2, MHALF, 1024,
                1);
        }
    }
}